// Round 10
// baseline (312.251 us; speedup 1.0000x reference)
//
#include <hip/hip_runtime.h>
#include <hip/hip_bf16.h>

#define N_NODES 100000
#define N_EDGES 800000
#define EPS 1e-5f
#define NBANK 32
#define HB_BLOCKS 256
#define HB_PER 3125          // 256 * 3125 = 800000 exactly
#define NBUCK 250            // coarse buckets
#define BUCKET_N 400         // 250 * 400 = 100000 exactly
#define MROW 68              // LDS mean row stride in dwords (64 + 4 pad)
#define WIN 4000             // degree-sort window (25 * 4000 = 100000)

typedef __attribute__((ext_vector_type(8))) short short8;
typedef __attribute__((ext_vector_type(4))) float floatx4;

__device__ __forceinline__ unsigned short f2b(float f) {
    unsigned int u = __float_as_uint(f);
    u = (u + 0x7fffu + ((u >> 16) & 1u)) >> 16;   // round-to-nearest-even
    return (unsigned short)u;
}
__device__ __forceinline__ float blo(unsigned int u) { return __uint_as_float(u << 16); }
__device__ __forceinline__ float bhi(unsigned int u) { return __uint_as_float(u & 0xffff0000u); }
__device__ __forceinline__ float b2f(unsigned short s) {
    return __uint_as_float(((unsigned int)s) << 16);
}

// ---------------- pack [Wl;Wr] (K=256 x Hreal) into MFMA B-fragment order ----
__device__ __forceinline__ void pack_one(const float* __restrict__ Wl,
                                         const float* __restrict__ Wr,
                                         unsigned short* __restrict__ out,
                                         int Hreal, int NCT, int tid) {
    int i = tid & 7;
    int lane = (tid >> 3) & 63;
    int q = tid >> 9;
    int c = q % NCT;
    int t = q / NCT;
    int k = t * 32 + (lane >> 4) * 8 + i;
    int n = c * 16 + (lane & 15);
    float v = 0.f;
    if (n < Hreal) v = (k < 128) ? Wl[k * Hreal + n] : Wr[(k - 128) * Hreal + n];
    out[tid] = f2b(v);
}

// ---------------- fused prep: cvt x->bf16 | coarse hist (LDS only) | pack_w --
__global__ void __launch_bounds__(256) prep_k(const float* __restrict__ x,
                                              unsigned short* __restrict__ o,
                                              const int* __restrict__ dst,
                                              unsigned int* __restrict__ bhist,
                                              const float* __restrict__ Wl0, const float* __restrict__ Wr0,
                                              const float* __restrict__ Wl1, const float* __restrict__ Wr1,
                                              const float* __restrict__ Wl2, const float* __restrict__ Wr2,
                                              unsigned short* __restrict__ W0p,
                                              unsigned short* __restrict__ W1p,
                                              unsigned short* __restrict__ W2p) {
    int b = blockIdx.x;
    if (b < 12500) {
        int i = b * 256 + threadIdx.x;   // 12500*256 float4 = N_NODES*128 floats exactly
        float4 v = ((const float4*)x)[i];
        ushort4 r;
        r.x = f2b(v.x); r.y = f2b(v.y); r.z = f2b(v.z); r.w = f2b(v.w);
        ((ushort4*)o)[i] = r;
        return;
    }
    if (b < 12756) {
        __shared__ unsigned int lh[NBUCK];
        int hb = b - 12500;
        if (threadIdx.x < NBUCK) lh[threadIdx.x] = 0;
        __syncthreads();
        int start = hb * HB_PER;
        for (int i = threadIdx.x; i < HB_PER; i += 256) {
            int d = dst[start + i];
            atomicAdd(&lh[(unsigned int)d / BUCKET_N], 1u);
        }
        __syncthreads();
        if (threadIdx.x < NBUCK) bhist[threadIdx.x * HB_BLOCKS + hb] = lh[threadIdx.x];
        return;
    }
    int tid = (b - 12756) * 256 + threadIdx.x;   // 304 blocks = 77824 threads exactly
    if (tid < 32768) pack_one(Wl0, Wr0, W0p, 128, 8, tid);
    else if (tid < 65536) pack_one(Wl1, Wr1, W1p, 128, 8, tid - 32768);
    else pack_one(Wl2, Wr2, W2p, 40, 3, tid - 65536);
}

// ---------------- bscan: exclusive scan of bhist[NBUCK][256] (64000 elems) ---
__global__ void __launch_bounds__(1024) bscan(unsigned int* __restrict__ A) {
    __shared__ unsigned int part[1024];
    int t = threadIdx.x;
    unsigned int v[64];
    unsigned int s = 0;
    if (t < 1000) {
#pragma unroll
        for (int i = 0; i < 64; i++) { v[i] = A[t * 64 + i]; s += v[i]; }
    }
    part[t] = s;
    __syncthreads();
    for (int off = 1; off < 1024; off <<= 1) {
        unsigned int add = (t >= off) ? part[t - off] : 0u;
        __syncthreads();
        part[t] += add;
        __syncthreads();
    }
    if (t < 1000) {
        unsigned int base = part[t] - s;  // exclusive
#pragma unroll
        for (int i = 0; i < 64; i++) { unsigned int old = v[i]; A[t * 64 + i] = base; base += old; }
    }
}

// ---------------- bscatter: edges -> ebuf grouped by coarse bucket -----------
__global__ void __launch_bounds__(256) bscatter(const int* __restrict__ src,
                                                const int* __restrict__ dst,
                                                const unsigned int* __restrict__ boffs,
                                                unsigned int* __restrict__ ebuf) {
    __shared__ unsigned int cur[NBUCK];
    if (threadIdx.x < NBUCK) cur[threadIdx.x] = boffs[threadIdx.x * HB_BLOCKS + blockIdx.x];
    __syncthreads();
    int start = blockIdx.x * HB_PER;
    for (int i = threadIdx.x; i < HB_PER; i += 256) {
        int d = dst[start + i];
        int s = src[start + i];
        unsigned int b = (unsigned int)d / BUCKET_N;
        unsigned int dl = (unsigned int)d - b * BUCKET_N;    // < 400, 9 bits
        unsigned int pos = atomicAdd(&cur[b], 1u);
        ebuf[pos] = (unsigned int)s | (dl << 17);
    }
}

// ---------------- bucket_sort: per-bucket LDS counting sort ------------------
// 250 blocks x 256 threads, one bucket (400 nodes, ~3200 edges) each.
__global__ void __launch_bounds__(256) bucket_sort_k(const unsigned int* __restrict__ ebuf,
                                                     const unsigned int* __restrict__ bhist,
                                                     unsigned int* __restrict__ rowptr,
                                                     int* __restrict__ srclist) {
    __shared__ unsigned int cntl[BUCKET_N];
    __shared__ unsigned int psum[256];
    int g = blockIdx.x;
    int t = threadIdx.x;
    unsigned int estart = bhist[g * HB_BLOCKS];
    unsigned int eend = (g == NBUCK - 1) ? N_EDGES : bhist[(g + 1) * HB_BLOCKS];

    if (t < BUCKET_N) cntl[t] = 0u;
    if (t + 256 < BUCKET_N) cntl[t + 256] = 0u;
    __syncthreads();

    for (unsigned int i = estart + t; i < eend; i += 256)
        atomicAdd(&cntl[ebuf[i] >> 17], 1u);
    __syncthreads();

    // exclusive scan over 400 counters: 2 per thread + block scan
    unsigned int l0 = 0, l1 = 0, s = 0;
    int base = t * 2;
    if (base < BUCKET_N) {
        unsigned int v0 = cntl[base];
        unsigned int v1 = (base + 1 < BUCKET_N) ? cntl[base + 1] : 0u;
        l0 = 0; l1 = v0; s = v0 + v1;
    }
    psum[t] = s;
    __syncthreads();
    for (int off = 1; off < 256; off <<= 1) {
        unsigned int add = (t >= off) ? psum[t - off] : 0u;
        __syncthreads();
        psum[t] += add;
        __syncthreads();
    }
    unsigned int tb = psum[t] - s;
    if (base < BUCKET_N) {
        unsigned int o0 = tb + l0;
        unsigned int o1 = tb + l1;
        cntl[base] = o0;                                // becomes cursor
        rowptr[g * BUCKET_N + base] = estart + o0;
        if (base + 1 < BUCKET_N) {
            cntl[base + 1] = o1;
            rowptr[g * BUCKET_N + base + 1] = estart + o1;
        }
    }
    if (g == NBUCK - 1 && t == 0) rowptr[N_NODES] = N_EDGES;
    __syncthreads();

    for (unsigned int i = estart + t; i < eend; i += 256) {
        unsigned int p = ebuf[i];
        unsigned int pos = atomicAdd(&cntl[p >> 17], 1u);
        srclist[estart + pos] = (int)(p & 0x1FFFFu);
    }
}

// ---------------- windowed degree sort (R17) ---------------------------------
// Sort by degree WITHIN 4000-node windows: blocks get 16 equal-degree nodes
// (wave balance) while all block traffic stays in a 1MB span (locality kept).
__global__ void __launch_bounds__(256) wsort_k(const unsigned int* __restrict__ rowptr,
                                               int* __restrict__ perm) {
    __shared__ unsigned int hist[64];
    __shared__ unsigned int curs[64];
    int base = blockIdx.x * WIN;
    int t = threadIdx.x;
    if (t < 64) hist[t] = 0;
    __syncthreads();
    for (int i = t; i < WIN; i += 256) {
        unsigned int d = rowptr[base + i + 1] - rowptr[base + i];
        if (d > 63u) d = 63u;
        atomicAdd(&hist[d], 1u);
    }
    __syncthreads();
    if (t == 0) {
        unsigned int s = 0;
#pragma unroll
        for (int i = 0; i < 64; i++) { curs[i] = s; s += hist[i]; }
    }
    __syncthreads();
    for (int i = t; i < WIN; i += 256) {
        unsigned int d = rowptr[base + i + 1] - rowptr[base + i];
        if (d > 63u) d = 63u;
        unsigned int pos = atomicAdd(&curs[d], 1u);
        perm[base + pos] = base + i;
    }
}

// ---------------- phase-1: aggregate 16 nodes, 1 node/group ------------------
template<int BN>
__device__ __forceinline__ void agg_phase16(const unsigned short* __restrict__ hb,
                                            const unsigned int* __restrict__ rowptr,
                                            const int* __restrict__ srclist,
                                            unsigned int* __restrict__ smean,
                                            const float* __restrict__ sc,
                                            const float* __restrict__ sh,
                                            const int* __restrict__ pblk,
                                            int wave, int g, int l) {
    const uint4* hp = (const uint4*)hb;
    int nl = wave * 4 + g;
    int node = pblk[nl];
    float f0 = 0.f, f1 = 0.f, f2 = 0.f, f3 = 0.f, f4 = 0.f, f5 = 0.f, f6 = 0.f, f7 = 0.f;
    float sc0r = 0.f, sc1r = 0.f, sc2r = 0.f, sc3r = 0.f, sc4r = 0.f, sc5r = 0.f, sc6r = 0.f, sc7r = 0.f;
    float sh0r = 0.f, sh1r = 0.f, sh2r = 0.f, sh3r = 0.f, sh4r = 0.f, sh5r = 0.f, sh6r = 0.f, sh7r = 0.f;
    if (BN) {
        const float* s0 = sc + l * 8;
        const float* s1 = sh + l * 8;
        sc0r = s0[0]; sc1r = s0[1]; sc2r = s0[2]; sc3r = s0[3];
        sc4r = s0[4]; sc5r = s0[5]; sc6r = s0[6]; sc7r = s0[7];
        sh0r = s1[0]; sh1r = s1[1]; sh2r = s1[2]; sh3r = s1[3];
        sh4r = s1[4]; sh5r = s1[5]; sh6r = s1[6]; sh7r = s1[7];
    }
    unsigned int b = rowptr[node], e = rowptr[node + 1];
    unsigned int p = b;
#define ACC8(U) { \
    if (BN) { \
        f0 += fmaxf(0.f, fmaf(blo(U.x), sc0r, sh0r)); \
        f1 += fmaxf(0.f, fmaf(bhi(U.x), sc1r, sh1r)); \
        f2 += fmaxf(0.f, fmaf(blo(U.y), sc2r, sh2r)); \
        f3 += fmaxf(0.f, fmaf(bhi(U.y), sc3r, sh3r)); \
        f4 += fmaxf(0.f, fmaf(blo(U.z), sc4r, sh4r)); \
        f5 += fmaxf(0.f, fmaf(bhi(U.z), sc5r, sh5r)); \
        f6 += fmaxf(0.f, fmaf(blo(U.w), sc6r, sh6r)); \
        f7 += fmaxf(0.f, fmaf(bhi(U.w), sc7r, sh7r)); \
    } else { \
        f0 += blo(U.x); f1 += bhi(U.x); f2 += blo(U.y); f3 += bhi(U.y); \
        f4 += blo(U.z); f5 += bhi(U.z); f6 += blo(U.w); f7 += bhi(U.w); \
    } }
    int s0 = 0, s1 = 0, s2 = 0, s3 = 0;
    bool have = (p + 4 <= e);
    if (have) { s0 = srclist[p]; s1 = srclist[p + 1]; s2 = srclist[p + 2]; s3 = srclist[p + 3]; }
    while (have) {
        uint4 u0 = hp[(size_t)s0 * 16 + l];
        uint4 u1 = hp[(size_t)s1 * 16 + l];
        uint4 u2 = hp[(size_t)s2 * 16 + l];
        uint4 u3 = hp[(size_t)s3 * 16 + l];
        p += 4;
        have = (p + 4 <= e);
        if (have) { s0 = srclist[p]; s1 = srclist[p + 1]; s2 = srclist[p + 2]; s3 = srclist[p + 3]; }
        ACC8(u0); ACC8(u1); ACC8(u2); ACC8(u3);
    }
    if (p + 2 <= e) {
        int t0 = srclist[p];
        int t1 = srclist[p + 1];
        uint4 u0 = hp[(size_t)t0 * 16 + l];
        uint4 u1 = hp[(size_t)t1 * 16 + l];
        ACC8(u0); ACC8(u1);
        p += 2;
    }
    if (p < e) {
        int t0 = srclist[p];
        uint4 u0 = hp[(size_t)t0 * 16 + l];
        ACC8(u0);
    }
#undef ACC8
    unsigned int deg = e - b;
    float r = 1.0f / (float)(deg > 1u ? deg : 1u);
    uint4 o;
    o.x = (unsigned int)f2b(f0 * r) | ((unsigned int)f2b(f1 * r) << 16);
    o.y = (unsigned int)f2b(f2 * r) | ((unsigned int)f2b(f3 * r) << 16);
    o.z = (unsigned int)f2b(f4 * r) | ((unsigned int)f2b(f5 * r) << 16);
    o.w = (unsigned int)f2b(f6 * r) | ((unsigned int)f2b(f7 * r) << 16);
    *(uint4*)&smean[nl * MROW + l * 4] = o;
}

// bn+relu+repack an 8-element bf16 fragment using LDS-staged sc/sh (root rows)
__device__ __forceinline__ short8 bn_pack8(short8 raw, const float* __restrict__ scb,
                                           const float* __restrict__ shb, int koff) {
    short8 r;
#pragma unroll
    for (int i = 0; i < 8; i++) {
        float v = b2f((unsigned short)raw[i]);
        v = fmaxf(0.f, fmaf(v, scb[koff + i], shb[koff + i]));
        r[i] = (short)f2b(v);
    }
    return r;
}

// ---------------- fused agg + GEMM L0/L1 + BN stats + bf16 C -----------------
// 16-row blocks, grid 6250; block's rows = perm[16b..16b+16) (window-sorted).
template<int BN>
__global__ void __launch_bounds__(256) gemm2f_k(const unsigned short* __restrict__ hb,
                                                const unsigned int* __restrict__ rowptr,
                                                const int* __restrict__ srclist,
                                                const int* __restrict__ perm,
                                                const float* __restrict__ sc,
                                                const float* __restrict__ sh,
                                                const unsigned short* __restrict__ Bp,
                                                unsigned short* __restrict__ outb,
                                                float* __restrict__ sums) {
    __shared__ unsigned int smean[16 * MROW];
    __shared__ float lds_s[128];
    __shared__ float lds_s2[128];
    __shared__ float scb[128];
    __shared__ float shb[128];
    __shared__ int pblk[16];
    int wave = threadIdx.x >> 6;
    int lane = threadIdx.x & 63;
    int quad = lane >> 4;
    int l15 = lane & 15;

    if (threadIdx.x < 128) {
        lds_s[threadIdx.x] = 0.f; lds_s2[threadIdx.x] = 0.f;
        if (BN) { scb[threadIdx.x] = sc[threadIdx.x]; shb[threadIdx.x] = sh[threadIdx.x]; }
    }
    if (threadIdx.x < 16) pblk[threadIdx.x] = perm[blockIdx.x * 16 + threadIdx.x];
    __syncthreads();

    agg_phase16<BN>(hb, rowptr, srclist, smean, sc, sh, pblk, wave, quad, l15);
    __syncthreads();

    floatx4 acc[2];
    acc[0] = (floatx4){0.f, 0.f, 0.f, 0.f};
    acc[1] = (floatx4){0.f, 0.f, 0.f, 0.f};

    int r0 = pblk[l15];

#pragma unroll
    for (int t = 0; t < 8; t++) {
        short8 a0;
        if (t < 4) {
            a0 = *(const short8*)&smean[l15 * MROW + t * 16 + quad * 4];
        } else {
            int koff = (t & 3) * 32 + quad * 8;
            short8 raw = *(const short8*)(hb + (size_t)r0 * 128 + koff);
            a0 = BN ? bn_pack8(raw, scb, shb, koff) : raw;
        }
#pragma unroll
        for (int c = 0; c < 2; c++) {
            int cidx = wave * 2 + c;
            short8 bf = *(const short8*)(Bp + ((size_t)(t * 8 + cidx) * 64 + lane) * 8);
            acc[c] = __builtin_amdgcn_mfma_f32_16x16x32_bf16(a0, bf, acc[c], 0, 0, 0);
        }
    }

#pragma unroll
    for (int c = 0; c < 2; c++) {
        int col = wave * 32 + c * 16 + l15;
        float s = 0.f, s2 = 0.f;
#pragma unroll
        for (int r = 0; r < 4; r++) {
            int row = pblk[quad * 4 + r];
            float v = acc[c][r];
            outb[(size_t)row * 128 + col] = f2b(v);
            s += v; s2 += v * v;
        }
        s += __shfl_xor(s, 16);  s += __shfl_xor(s, 32);
        s2 += __shfl_xor(s2, 16); s2 += __shfl_xor(s2, 32);
        if (quad == 0) {
            atomicAdd(&lds_s[col], s);
            atomicAdd(&lds_s2[col], s2);
        }
    }

    __syncthreads();
    if (threadIdx.x < 128) {
        int bank = blockIdx.x & (NBANK - 1);
        atomicAdd(&sums[bank * 256 + threadIdx.x], lds_s[threadIdx.x]);
        atomicAdd(&sums[bank * 256 + 128 + threadIdx.x], lds_s2[threadIdx.x]);
    }
}

// ---------------- layer-2 dense: P = h2@Wl2 (bf16, 40 cols), Q = h2@Wr2+b2 ---
__global__ void __launch_bounds__(192) dense_k(const unsigned short* __restrict__ hb,
                                               const float* __restrict__ sc,
                                               const float* __restrict__ sh,
                                               const unsigned short* __restrict__ Bp,
                                               const float* __restrict__ bias,
                                               unsigned short* __restrict__ P,
                                               float* __restrict__ Q) {
    __shared__ float scb[128];
    __shared__ float shb[128];
    int wave = threadIdx.x >> 6;
    int lane = threadIdx.x & 63;
    int quad = lane >> 4;
    int l15 = lane & 15;
    int blockrow = blockIdx.x * 16;

    if (threadIdx.x < 128) { scb[threadIdx.x] = sc[threadIdx.x]; shb[threadIdx.x] = sh[threadIdx.x]; }
    __syncthreads();

    int r0 = blockrow + l15;
    short8 af[4];
#pragma unroll
    for (int t = 0; t < 4; t++) {
        int koff = t * 32 + quad * 8;
        short8 raw = *(const short8*)(hb + (size_t)r0 * 128 + koff);
        af[t] = bn_pack8(raw, scb, shb, koff);
    }

    floatx4 aP = (floatx4){0.f, 0.f, 0.f, 0.f};
    floatx4 aQ = (floatx4){0.f, 0.f, 0.f, 0.f};
#pragma unroll
    for (int t = 0; t < 4; t++) {
        short8 bl = *(const short8*)(Bp + ((size_t)(t * 3 + wave) * 64 + lane) * 8);
        aP = __builtin_amdgcn_mfma_f32_16x16x32_bf16(af[t], bl, aP, 0, 0, 0);
    }
#pragma unroll
    for (int t = 0; t < 4; t++) {
        short8 br = *(const short8*)(Bp + ((size_t)((t + 4) * 3 + wave) * 64 + lane) * 8);
        aQ = __builtin_amdgcn_mfma_f32_16x16x32_bf16(af[t], br, aQ, 0, 0, 0);
    }
    int col = wave * 16 + l15;
    if (col < 40) {
#pragma unroll
        for (int r = 0; r < 4; r++) {
            int row = blockrow + quad * 4 + r;
            P[(size_t)row * 40 + col] = f2b(aP[r]);
            Q[(size_t)row * 40 + col] = aQ[r] + bias[col];
        }
    }
}

// ---------------- layer-2 aggregate: out = mean(P[src]) + Q ------------------
__global__ void __launch_bounds__(256) agg40_k(const unsigned short* __restrict__ P,
                                               const unsigned int* __restrict__ rowptr,
                                               const int* __restrict__ srclist,
                                               const float* __restrict__ Q,
                                               float* __restrict__ out) {
    int tid = threadIdx.x;
    int g = tid >> 3;        // group 0..31
    int l = tid & 7;         // lane in group
    int ll = l < 5 ? l : 0;  // lanes 5-7 alias lane 0 (no extra lines)
    int node = blockIdx.x * 32 + g;   // 3125*32 = 100000 exactly
    const uint4* pp = (const uint4*)P;
    float f0 = 0.f, f1 = 0.f, f2 = 0.f, f3 = 0.f, f4 = 0.f, f5 = 0.f, f6 = 0.f, f7 = 0.f;
    unsigned int b = rowptr[node], e = rowptr[node + 1];
    unsigned int p = b;
#define ACC8(U) { f0 += blo(U.x); f1 += bhi(U.x); f2 += blo(U.y); f3 += bhi(U.y); \
                  f4 += blo(U.z); f5 += bhi(U.z); f6 += blo(U.w); f7 += bhi(U.w); }
    int s0 = 0, s1 = 0, s2 = 0, s3 = 0;
    bool have = (p + 4 <= e);
    if (have) { s0 = srclist[p]; s1 = srclist[p + 1]; s2 = srclist[p + 2]; s3 = srclist[p + 3]; }
    while (have) {
        uint4 u0 = pp[(size_t)s0 * 5 + ll];
        uint4 u1 = pp[(size_t)s1 * 5 + ll];
        uint4 u2 = pp[(size_t)s2 * 5 + ll];
        uint4 u3 = pp[(size_t)s3 * 5 + ll];
        p += 4;
        have = (p + 4 <= e);
        if (have) { s0 = srclist[p]; s1 = srclist[p + 1]; s2 = srclist[p + 2]; s3 = srclist[p + 3]; }
        ACC8(u0); ACC8(u1); ACC8(u2); ACC8(u3);
    }
    if (p + 2 <= e) {
        int t0 = srclist[p];
        int t1 = srclist[p + 1];
        uint4 u0 = pp[(size_t)t0 * 5 + ll];
        uint4 u1 = pp[(size_t)t1 * 5 + ll];
        ACC8(u0); ACC8(u1);
        p += 2;
    }
    if (p < e) {
        int t0 = srclist[p];
        uint4 u0 = pp[(size_t)t0 * 5 + ll];
        ACC8(u0);
    }
#undef ACC8
    unsigned int deg = e - b;
    float r = 1.0f / (float)(deg > 1u ? deg : 1u);
    if (l < 5) {   // cols l*8 .. l*8+8 of 40
        size_t base = (size_t)node * 40 + l * 8;
        float4 o1, o2;
        o1.x = f0 * r + Q[base + 0]; o1.y = f1 * r + Q[base + 1];
        o1.z = f2 * r + Q[base + 2]; o1.w = f3 * r + Q[base + 3];
        o2.x = f4 * r + Q[base + 4]; o2.y = f5 * r + Q[base + 5];
        o2.z = f6 * r + Q[base + 6]; o2.w = f7 * r + Q[base + 7];
        *(float4*)(out + base) = o1;
        *(float4*)(out + base + 4) = o2;
    }
}

// ---------------- BN finalize (reduce 32 banks) ------------------------------
__global__ void bn_finalize(const float* __restrict__ sums, const float* __restrict__ g,
                            const float* __restrict__ be, float* __restrict__ sc,
                            float* __restrict__ sh) {
    __shared__ float lds[256];
    int t = threadIdx.x;
    float s = 0.f;
#pragma unroll 8
    for (int bk = 0; bk < NBANK; bk++) s += sums[bk * 256 + t];
    lds[t] = s;
    __syncthreads();
    if (t < 128) {
        float inv_n = 1.0f / (float)N_NODES;
        float mu = lds[t] * inv_n;
        float var = lds[128 + t] * inv_n - mu * mu;
        float sf = g[t] * rsqrtf(var + EPS);
        sc[t] = sf;
        sh[t] = be[t] - mu * sf;
    }
}

// ---------------- host ----------------
extern "C" void kernel_launch(void* const* d_in, const int* in_sizes, int n_in,
                              void* d_out, int out_size, void* d_ws, size_t ws_size,
                              hipStream_t stream) {
    const float* x   = (const float*)d_in[0];
    const int* ei    = (const int*)d_in[1];     // [2, E] int32: row 0 = src, row 1 = dst
    const float* Wl0 = (const float*)d_in[2];
    const float* Wr0 = (const float*)d_in[3];
    const float* Wl1 = (const float*)d_in[4];
    const float* Wr1 = (const float*)d_in[5];
    const float* Wl2 = (const float*)d_in[6];
    const float* Wr2 = (const float*)d_in[7];
    const float* b2  = (const float*)d_in[8];
    const float* g0  = (const float*)d_in[9];
    const float* be0 = (const float*)d_in[10];
    const float* g1  = (const float*)d_in[11];
    const float* be1 = (const float*)d_in[12];

    char* ws = (char*)d_ws;
    size_t off = 0;
    auto alloc = [&](size_t bytes) -> void* {
        void* p = ws + off;
        off += (bytes + 4095) & ~(size_t)4095;
        return p;
    };

    const size_t NB16 = (size_t)N_NODES * 128 * 2;  // 25.6 MB bf16 feature buffer
    unsigned short* xb   = (unsigned short*)alloc(NB16);   // x bf16; reused as Q (fp32 16MB)
    unsigned short* C0b  = (unsigned short*)alloc(NB16);   // layer-0 pre-BN C; reused as P40
    unsigned short* C1b  = (unsigned short*)alloc(NB16);   // layer-1 pre-BN C
    float* sums0         = (float*)alloc(NBANK * 256 * 4); // contiguous with sums1
    float* sums1         = (float*)alloc(NBANK * 256 * 4);
    unsigned int* rowptr = (unsigned int*)alloc((size_t)(N_NODES + 1) * 4);
    int* srclist         = (int*)alloc((size_t)N_EDGES * 4);
    unsigned int* ebuf   = (unsigned int*)alloc((size_t)N_EDGES * 4);
    unsigned int* bhist  = (unsigned int*)alloc((size_t)NBUCK * HB_BLOCKS * 4);
    int* perm            = (int*)alloc((size_t)N_NODES * 4);
    float* sc            = (float*)alloc(128 * 4);
    float* sh            = (float*)alloc(128 * 4);
    unsigned short* W0p  = (unsigned short*)alloc(8 * 8 * 64 * 8 * 2);
    unsigned short* W1p  = (unsigned short*)alloc(8 * 8 * 64 * 8 * 2);
    unsigned short* W2p  = (unsigned short*)alloc(3 * 8 * 64 * 8 * 2);

    unsigned short* P40  = C0b;           // 8 MB, C0 dead after layer-1 gemm
    float* Q             = (float*)xb;    // 16 MB, xb dead after layer-0 gemm

    const int* srcp = ei;
    const int* dstp = ei + N_EDGES;

    hipMemsetAsync(sums0, 0, (size_t)2 * NBANK * 256 * 4, stream);

    // fused cvt + coarse hist + weight pack
    prep_k<<<13060, 256, 0, stream>>>(x, xb, dstp, bhist,
                                      Wl0, Wr0, Wl1, Wr1, Wl2, Wr2, W0p, W1p, W2p);

    // CSR: coarse partition (250 buckets) then per-bucket LDS counting sort
    bscan<<<1, 1024, 0, stream>>>(bhist);
    bscatter<<<HB_BLOCKS, 256, 0, stream>>>(srcp, dstp, bhist, ebuf);
    bucket_sort_k<<<NBUCK, 256, 0, stream>>>(ebuf, bhist, rowptr, srclist);

    // windowed degree-balance permutation (reads degrees from rowptr)
    wsort_k<<<N_NODES / WIN, 256, 0, stream>>>(rowptr, perm);

    // layer 0: agg+gemm from x (no input BN) -> C0, stats0
    gemm2f_k<0><<<6250, 256, 0, stream>>>(xb, rowptr, srclist, perm, nullptr, nullptr, W0p, C0b, sums0);
    bn_finalize<<<1, 256, 0, stream>>>(sums0, g0, be0, sc, sh);

    // layer 1: agg+gemm from C0 with inline relu(bn0) -> C1, stats1
    gemm2f_k<1><<<6250, 256, 0, stream>>>(C0b, rowptr, srclist, perm, sc, sh, W1p, C1b, sums1);
    bn_finalize<<<1, 256, 0, stream>>>(sums1, g1, be1, sc, sh);

    // layer 2: transform-first (mean is linear)
    dense_k<<<6250, 192, 0, stream>>>(C1b, sc, sh, W2p, b2, P40, Q);
    agg40_k<<<3125, 256, 0, stream>>>(P40, rowptr, srclist, Q, (float*)d_out);

    (void)in_sizes; (void)n_in; (void)out_size; (void)ws_size;
}

// Round 11
// 306.874 us; speedup vs baseline: 1.0175x; 1.0175x over previous
//
#include <hip/hip_runtime.h>
#include <hip/hip_bf16.h>

#define N_NODES 100000
#define N_EDGES 800000
#define EPS 1e-5f
#define NBANK 32
#define HB_BLOCKS 256
#define HB_PER 3125          // 256 * 3125 = 800000 exactly
#define NBUCK 250            // coarse buckets
#define BUCKET_N 400         // 250 * 400 = 100000 exactly
#define MROW 68              // LDS mean row stride in dwords (64 + 4 pad)

typedef __attribute__((ext_vector_type(8))) short short8;
typedef __attribute__((ext_vector_type(4))) float floatx4;

__device__ __forceinline__ unsigned short f2b(float f) {
    unsigned int u = __float_as_uint(f);
    u = (u + 0x7fffu + ((u >> 16) & 1u)) >> 16;   // round-to-nearest-even
    return (unsigned short)u;
}
__device__ __forceinline__ float blo(unsigned int u) { return __uint_as_float(u << 16); }
__device__ __forceinline__ float bhi(unsigned int u) { return __uint_as_float(u & 0xffff0000u); }
__device__ __forceinline__ float b2f(unsigned short s) {
    return __uint_as_float(((unsigned int)s) << 16);
}

// ---------------- pack [Wl;Wr] (K=256 x Hreal) into MFMA B-fragment order ----
__device__ __forceinline__ void pack_one(const float* __restrict__ Wl,
                                         const float* __restrict__ Wr,
                                         unsigned short* __restrict__ out,
                                         int Hreal, int NCT, int tid) {
    int i = tid & 7;
    int lane = (tid >> 3) & 63;
    int q = tid >> 9;
    int c = q % NCT;
    int t = q / NCT;
    int k = t * 32 + (lane >> 4) * 8 + i;
    int n = c * 16 + (lane & 15);
    float v = 0.f;
    if (n < Hreal) v = (k < 128) ? Wl[k * Hreal + n] : Wr[(k - 128) * Hreal + n];
    out[tid] = f2b(v);
}

// ---------------- fused prep: cvt x->bf16 | coarse hist (LDS only) | pack_w --
// (R18: wsort/perm REVERTED — R17 measured it as a wash per-kernel and a net
//  regression with the extra dispatch: balance +7% BW but +5% FETCH, occupancy
//  unmoved at 51%. Wave imbalance is NOT the occupancy sag; consecutive-node
//  blocks keep the clean 101/31 MB traffic profile.)
__global__ void __launch_bounds__(256) prep_k(const float* __restrict__ x,
                                              unsigned short* __restrict__ o,
                                              const int* __restrict__ dst,
                                              unsigned int* __restrict__ bhist,
                                              const float* __restrict__ Wl0, const float* __restrict__ Wr0,
                                              const float* __restrict__ Wl1, const float* __restrict__ Wr1,
                                              const float* __restrict__ Wl2, const float* __restrict__ Wr2,
                                              unsigned short* __restrict__ W0p,
                                              unsigned short* __restrict__ W1p,
                                              unsigned short* __restrict__ W2p) {
    int b = blockIdx.x;
    if (b < 12500) {
        int i = b * 256 + threadIdx.x;   // 12500*256 float4 = N_NODES*128 floats exactly
        float4 v = ((const float4*)x)[i];
        ushort4 r;
        r.x = f2b(v.x); r.y = f2b(v.y); r.z = f2b(v.z); r.w = f2b(v.w);
        ((ushort4*)o)[i] = r;
        return;
    }
    if (b < 12756) {
        __shared__ unsigned int lh[NBUCK];
        int hb = b - 12500;
        if (threadIdx.x < NBUCK) lh[threadIdx.x] = 0;
        __syncthreads();
        int start = hb * HB_PER;
        for (int i = threadIdx.x; i < HB_PER; i += 256) {
            int d = dst[start + i];
            atomicAdd(&lh[(unsigned int)d / BUCKET_N], 1u);
        }
        __syncthreads();
        if (threadIdx.x < NBUCK) bhist[threadIdx.x * HB_BLOCKS + hb] = lh[threadIdx.x];
        return;
    }
    int tid = (b - 12756) * 256 + threadIdx.x;   // 304 blocks = 77824 threads exactly
    if (tid < 32768) pack_one(Wl0, Wr0, W0p, 128, 8, tid);
    else if (tid < 65536) pack_one(Wl1, Wr1, W1p, 128, 8, tid - 32768);
    else pack_one(Wl2, Wr2, W2p, 40, 3, tid - 65536);
}

// ---------------- bscan: exclusive scan of bhist[NBUCK][256] (64000 elems) ---
__global__ void __launch_bounds__(1024) bscan(unsigned int* __restrict__ A) {
    __shared__ unsigned int part[1024];
    int t = threadIdx.x;
    unsigned int v[64];
    unsigned int s = 0;
    if (t < 1000) {
#pragma unroll
        for (int i = 0; i < 64; i++) { v[i] = A[t * 64 + i]; s += v[i]; }
    }
    part[t] = s;
    __syncthreads();
    for (int off = 1; off < 1024; off <<= 1) {
        unsigned int add = (t >= off) ? part[t - off] : 0u;
        __syncthreads();
        part[t] += add;
        __syncthreads();
    }
    if (t < 1000) {
        unsigned int base = part[t] - s;  // exclusive
#pragma unroll
        for (int i = 0; i < 64; i++) { unsigned int old = v[i]; A[t * 64 + i] = base; base += old; }
    }
}

// ---------------- bscatter: edges -> ebuf grouped by coarse bucket -----------
__global__ void __launch_bounds__(256) bscatter(const int* __restrict__ src,
                                                const int* __restrict__ dst,
                                                const unsigned int* __restrict__ boffs,
                                                unsigned int* __restrict__ ebuf) {
    __shared__ unsigned int cur[NBUCK];
    if (threadIdx.x < NBUCK) cur[threadIdx.x] = boffs[threadIdx.x * HB_BLOCKS + blockIdx.x];
    __syncthreads();
    int start = blockIdx.x * HB_PER;
    for (int i = threadIdx.x; i < HB_PER; i += 256) {
        int d = dst[start + i];
        int s = src[start + i];
        unsigned int b = (unsigned int)d / BUCKET_N;
        unsigned int dl = (unsigned int)d - b * BUCKET_N;    // < 400, 9 bits
        unsigned int pos = atomicAdd(&cur[b], 1u);
        ebuf[pos] = (unsigned int)s | (dl << 17);
    }
}

// ---------------- bucket_sort: per-bucket LDS counting sort ------------------
// 250 blocks x 256 threads, one bucket (400 nodes, ~3200 edges) each.
__global__ void __launch_bounds__(256) bucket_sort_k(const unsigned int* __restrict__ ebuf,
                                                     const unsigned int* __restrict__ bhist,
                                                     unsigned int* __restrict__ rowptr,
                                                     int* __restrict__ srclist) {
    __shared__ unsigned int cntl[BUCKET_N];
    __shared__ unsigned int psum[256];
    int g = blockIdx.x;
    int t = threadIdx.x;
    unsigned int estart = bhist[g * HB_BLOCKS];
    unsigned int eend = (g == NBUCK - 1) ? N_EDGES : bhist[(g + 1) * HB_BLOCKS];

    if (t < BUCKET_N) cntl[t] = 0u;
    if (t + 256 < BUCKET_N) cntl[t + 256] = 0u;
    __syncthreads();

    for (unsigned int i = estart + t; i < eend; i += 256)
        atomicAdd(&cntl[ebuf[i] >> 17], 1u);
    __syncthreads();

    // exclusive scan over 400 counters: 2 per thread + block scan
    unsigned int l0 = 0, l1 = 0, s = 0;
    int base = t * 2;
    if (base < BUCKET_N) {
        unsigned int v0 = cntl[base];
        unsigned int v1 = (base + 1 < BUCKET_N) ? cntl[base + 1] : 0u;
        l0 = 0; l1 = v0; s = v0 + v1;
    }
    psum[t] = s;
    __syncthreads();
    for (int off = 1; off < 256; off <<= 1) {
        unsigned int add = (t >= off) ? psum[t - off] : 0u;
        __syncthreads();
        psum[t] += add;
        __syncthreads();
    }
    unsigned int tb = psum[t] - s;
    if (base < BUCKET_N) {
        unsigned int o0 = tb + l0;
        unsigned int o1 = tb + l1;
        cntl[base] = o0;                                // becomes cursor
        rowptr[g * BUCKET_N + base] = estart + o0;
        if (base + 1 < BUCKET_N) {
            cntl[base + 1] = o1;
            rowptr[g * BUCKET_N + base + 1] = estart + o1;
        }
    }
    if (g == NBUCK - 1 && t == 0) rowptr[N_NODES] = N_EDGES;
    __syncthreads();

    for (unsigned int i = estart + t; i < eend; i += 256) {
        unsigned int p = ebuf[i];
        unsigned int pos = atomicAdd(&cntl[p >> 17], 1u);
        srclist[estart + pos] = (int)(p & 0x1FFFFu);
    }
}

// ---------------- phase-1: aggregate 16 nodes, 1 node/group ------------------
// R13/R14 structure: unroll-4, consecutive nodes, srclist prefetch pipeline,
// inline relu(bn) on the BN=1 path (sc/sh in 16 regs).
template<int BN>
__device__ __forceinline__ void agg_phase16(const unsigned short* __restrict__ hb,
                                            const unsigned int* __restrict__ rowptr,
                                            const int* __restrict__ srclist,
                                            unsigned int* __restrict__ smean,
                                            const float* __restrict__ sc,
                                            const float* __restrict__ sh,
                                            int wave, int g, int l, int blockrow) {
    const uint4* hp = (const uint4*)hb;
    int nl = wave * 4 + g;
    int node = blockrow + nl;   // grid is N/16 exactly -> always < N_NODES
    float f0 = 0.f, f1 = 0.f, f2 = 0.f, f3 = 0.f, f4 = 0.f, f5 = 0.f, f6 = 0.f, f7 = 0.f;
    float sc0r = 0.f, sc1r = 0.f, sc2r = 0.f, sc3r = 0.f, sc4r = 0.f, sc5r = 0.f, sc6r = 0.f, sc7r = 0.f;
    float sh0r = 0.f, sh1r = 0.f, sh2r = 0.f, sh3r = 0.f, sh4r = 0.f, sh5r = 0.f, sh6r = 0.f, sh7r = 0.f;
    if (BN) {
        const float* s0 = sc + l * 8;
        const float* s1 = sh + l * 8;
        sc0r = s0[0]; sc1r = s0[1]; sc2r = s0[2]; sc3r = s0[3];
        sc4r = s0[4]; sc5r = s0[5]; sc6r = s0[6]; sc7r = s0[7];
        sh0r = s1[0]; sh1r = s1[1]; sh2r = s1[2]; sh3r = s1[3];
        sh4r = s1[4]; sh5r = s1[5]; sh6r = s1[6]; sh7r = s1[7];
    }
    unsigned int b = rowptr[node], e = rowptr[node + 1];
    unsigned int p = b;
#define ACC8(U) { \
    if (BN) { \
        f0 += fmaxf(0.f, fmaf(blo(U.x), sc0r, sh0r)); \
        f1 += fmaxf(0.f, fmaf(bhi(U.x), sc1r, sh1r)); \
        f2 += fmaxf(0.f, fmaf(blo(U.y), sc2r, sh2r)); \
        f3 += fmaxf(0.f, fmaf(bhi(U.y), sc3r, sh3r)); \
        f4 += fmaxf(0.f, fmaf(blo(U.z), sc4r, sh4r)); \
        f5 += fmaxf(0.f, fmaf(bhi(U.z), sc5r, sh5r)); \
        f6 += fmaxf(0.f, fmaf(blo(U.w), sc6r, sh6r)); \
        f7 += fmaxf(0.f, fmaf(bhi(U.w), sc7r, sh7r)); \
    } else { \
        f0 += blo(U.x); f1 += bhi(U.x); f2 += blo(U.y); f3 += bhi(U.y); \
        f4 += blo(U.z); f5 += bhi(U.z); f6 += blo(U.w); f7 += bhi(U.w); \
    } }
    int s0 = 0, s1 = 0, s2 = 0, s3 = 0;
    bool have = (p + 4 <= e);
    if (have) { s0 = srclist[p]; s1 = srclist[p + 1]; s2 = srclist[p + 2]; s3 = srclist[p + 3]; }
    while (have) {
        uint4 u0 = hp[(size_t)s0 * 16 + l];
        uint4 u1 = hp[(size_t)s1 * 16 + l];
        uint4 u2 = hp[(size_t)s2 * 16 + l];
        uint4 u3 = hp[(size_t)s3 * 16 + l];
        p += 4;
        have = (p + 4 <= e);
        if (have) { s0 = srclist[p]; s1 = srclist[p + 1]; s2 = srclist[p + 2]; s3 = srclist[p + 3]; }
        ACC8(u0); ACC8(u1); ACC8(u2); ACC8(u3);
    }
    if (p + 2 <= e) {
        int t0 = srclist[p];
        int t1 = srclist[p + 1];
        uint4 u0 = hp[(size_t)t0 * 16 + l];
        uint4 u1 = hp[(size_t)t1 * 16 + l];
        ACC8(u0); ACC8(u1);
        p += 2;
    }
    if (p < e) {
        int t0 = srclist[p];
        uint4 u0 = hp[(size_t)t0 * 16 + l];
        ACC8(u0);
    }
#undef ACC8
    unsigned int deg = e - b;
    float r = 1.0f / (float)(deg > 1u ? deg : 1u);
    uint4 o;
    o.x = (unsigned int)f2b(f0 * r) | ((unsigned int)f2b(f1 * r) << 16);
    o.y = (unsigned int)f2b(f2 * r) | ((unsigned int)f2b(f3 * r) << 16);
    o.z = (unsigned int)f2b(f4 * r) | ((unsigned int)f2b(f5 * r) << 16);
    o.w = (unsigned int)f2b(f6 * r) | ((unsigned int)f2b(f7 * r) << 16);
    *(uint4*)&smean[nl * MROW + l * 4] = o;
}

// bn+relu+repack an 8-element bf16 fragment using LDS-staged sc/sh (root rows)
__device__ __forceinline__ short8 bn_pack8(short8 raw, const float* __restrict__ scb,
                                           const float* __restrict__ shb, int koff) {
    short8 r;
#pragma unroll
    for (int i = 0; i < 8; i++) {
        float v = b2f((unsigned short)raw[i]);
        v = fmaxf(0.f, fmaf(v, scb[koff + i], shb[koff + i]));
        r[i] = (short)f2b(v);
    }
    return r;
}

// ---------------- fused agg + GEMM L0/L1 + BN stats + bf16 C -----------------
template<int BN>
__global__ void __launch_bounds__(256) gemm2f_k(const unsigned short* __restrict__ hb,
                                                const unsigned int* __restrict__ rowptr,
                                                const int* __restrict__ srclist,
                                                const float* __restrict__ sc,
                                                const float* __restrict__ sh,
                                                const unsigned short* __restrict__ Bp,
                                                unsigned short* __restrict__ outb,
                                                float* __restrict__ sums) {
    __shared__ unsigned int smean[16 * MROW];
    __shared__ float lds_s[128];
    __shared__ float lds_s2[128];
    __shared__ float scb[128];
    __shared__ float shb[128];
    int wave = threadIdx.x >> 6;
    int lane = threadIdx.x & 63;
    int quad = lane >> 4;
    int l15 = lane & 15;
    int blockrow = blockIdx.x * 16;

    if (threadIdx.x < 128) {
        lds_s[threadIdx.x] = 0.f; lds_s2[threadIdx.x] = 0.f;
        if (BN) { scb[threadIdx.x] = sc[threadIdx.x]; shb[threadIdx.x] = sh[threadIdx.x]; }
    }
    if (BN) __syncthreads();   // scb/shb visible to phase 2 root loads

    agg_phase16<BN>(hb, rowptr, srclist, smean, sc, sh, wave, quad, l15, blockrow);
    __syncthreads();

    floatx4 acc[2];
    acc[0] = (floatx4){0.f, 0.f, 0.f, 0.f};
    acc[1] = (floatx4){0.f, 0.f, 0.f, 0.f};

    int r0 = blockrow + l15;   // always < N_NODES (exact division)

#pragma unroll
    for (int t = 0; t < 8; t++) {
        short8 a0;
        if (t < 4) {
            a0 = *(const short8*)&smean[l15 * MROW + t * 16 + quad * 4];
        } else {
            int koff = (t & 3) * 32 + quad * 8;
            short8 raw = *(const short8*)(hb + (size_t)r0 * 128 + koff);
            a0 = BN ? bn_pack8(raw, scb, shb, koff) : raw;
        }
#pragma unroll
        for (int c = 0; c < 2; c++) {
            int cidx = wave * 2 + c;
            short8 bf = *(const short8*)(Bp + ((size_t)(t * 8 + cidx) * 64 + lane) * 8);
            acc[c] = __builtin_amdgcn_mfma_f32_16x16x32_bf16(a0, bf, acc[c], 0, 0, 0);
        }
    }

#pragma unroll
    for (int c = 0; c < 2; c++) {
        int col = wave * 32 + c * 16 + l15;
        float s = 0.f, s2 = 0.f;
#pragma unroll
        for (int r = 0; r < 4; r++) {
            int row = blockrow + quad * 4 + r;
            float v = acc[c][r];
            outb[(size_t)row * 128 + col] = f2b(v);
            s += v; s2 += v * v;
        }
        s += __shfl_xor(s, 16);  s += __shfl_xor(s, 32);
        s2 += __shfl_xor(s2, 16); s2 += __shfl_xor(s2, 32);
        if (quad == 0) {
            atomicAdd(&lds_s[col], s);
            atomicAdd(&lds_s2[col], s2);
        }
    }

    __syncthreads();
    if (threadIdx.x < 128) {
        int bank = blockIdx.x & (NBANK - 1);
        atomicAdd(&sums[bank * 256 + threadIdx.x], lds_s[threadIdx.x]);
        atomicAdd(&sums[bank * 256 + 128 + threadIdx.x], lds_s2[threadIdx.x]);
    }
}

// ---------------- layer-2 dense: P = h2@Wl2 (bf16, 40 cols), Q = h2@Wr2+b2 ---
__global__ void __launch_bounds__(192) dense_k(const unsigned short* __restrict__ hb,
                                               const float* __restrict__ sc,
                                               const float* __restrict__ sh,
                                               const unsigned short* __restrict__ Bp,
                                               const float* __restrict__ bias,
                                               unsigned short* __restrict__ P,
                                               float* __restrict__ Q) {
    __shared__ float scb[128];
    __shared__ float shb[128];
    int wave = threadIdx.x >> 6;
    int lane = threadIdx.x & 63;
    int quad = lane >> 4;
    int l15 = lane & 15;
    int blockrow = blockIdx.x * 16;

    if (threadIdx.x < 128) { scb[threadIdx.x] = sc[threadIdx.x]; shb[threadIdx.x] = sh[threadIdx.x]; }
    __syncthreads();

    int r0 = blockrow + l15;
    short8 af[4];
#pragma unroll
    for (int t = 0; t < 4; t++) {
        int koff = t * 32 + quad * 8;
        short8 raw = *(const short8*)(hb + (size_t)r0 * 128 + koff);
        af[t] = bn_pack8(raw, scb, shb, koff);
    }

    floatx4 aP = (floatx4){0.f, 0.f, 0.f, 0.f};
    floatx4 aQ = (floatx4){0.f, 0.f, 0.f, 0.f};
#pragma unroll
    for (int t = 0; t < 4; t++) {
        short8 bl = *(const short8*)(Bp + ((size_t)(t * 3 + wave) * 64 + lane) * 8);
        aP = __builtin_amdgcn_mfma_f32_16x16x32_bf16(af[t], bl, aP, 0, 0, 0);
    }
#pragma unroll
    for (int t = 0; t < 4; t++) {
        short8 br = *(const short8*)(Bp + ((size_t)((t + 4) * 3 + wave) * 64 + lane) * 8);
        aQ = __builtin_amdgcn_mfma_f32_16x16x32_bf16(af[t], br, aQ, 0, 0, 0);
    }
    int col = wave * 16 + l15;
    if (col < 40) {
#pragma unroll
        for (int r = 0; r < 4; r++) {
            int row = blockrow + quad * 4 + r;
            P[(size_t)row * 40 + col] = f2b(aP[r]);
            Q[(size_t)row * 40 + col] = aQ[r] + bias[col];
        }
    }
}

// ---------------- layer-2 aggregate: out = mean(P[src]) + Q ------------------
__global__ void __launch_bounds__(256) agg40_k(const unsigned short* __restrict__ P,
                                               const unsigned int* __restrict__ rowptr,
                                               const int* __restrict__ srclist,
                                               const float* __restrict__ Q,
                                               float* __restrict__ out) {
    int tid = threadIdx.x;
    int g = tid >> 3;        // group 0..31
    int l = tid & 7;         // lane in group
    int ll = l < 5 ? l : 0;  // lanes 5-7 alias lane 0 (no extra lines)
    int node = blockIdx.x * 32 + g;   // 3125*32 = 100000 exactly
    const uint4* pp = (const uint4*)P;
    float f0 = 0.f, f1 = 0.f, f2 = 0.f, f3 = 0.f, f4 = 0.f, f5 = 0.f, f6 = 0.f, f7 = 0.f;
    unsigned int b = rowptr[node], e = rowptr[node + 1];
    unsigned int p = b;
#define ACC8(U) { f0 += blo(U.x); f1 += bhi(U.x); f2 += blo(U.y); f3 += bhi(U.y); \
                  f4 += blo(U.z); f5 += bhi(U.z); f6 += blo(U.w); f7 += bhi(U.w); }
    int s0 = 0, s1 = 0, s2 = 0, s3 = 0;
    bool have = (p + 4 <= e);
    if (have) { s0 = srclist[p]; s1 = srclist[p + 1]; s2 = srclist[p + 2]; s3 = srclist[p + 3]; }
    while (have) {
        uint4 u0 = pp[(size_t)s0 * 5 + ll];
        uint4 u1 = pp[(size_t)s1 * 5 + ll];
        uint4 u2 = pp[(size_t)s2 * 5 + ll];
        uint4 u3 = pp[(size_t)s3 * 5 + ll];
        p += 4;
        have = (p + 4 <= e);
        if (have) { s0 = srclist[p]; s1 = srclist[p + 1]; s2 = srclist[p + 2]; s3 = srclist[p + 3]; }
        ACC8(u0); ACC8(u1); ACC8(u2); ACC8(u3);
    }
    if (p + 2 <= e) {
        int t0 = srclist[p];
        int t1 = srclist[p + 1];
        uint4 u0 = pp[(size_t)t0 * 5 + ll];
        uint4 u1 = pp[(size_t)t1 * 5 + ll];
        ACC8(u0); ACC8(u1);
        p += 2;
    }
    if (p < e) {
        int t0 = srclist[p];
        uint4 u0 = pp[(size_t)t0 * 5 + ll];
        ACC8(u0);
    }
#undef ACC8
    unsigned int deg = e - b;
    float r = 1.0f / (float)(deg > 1u ? deg : 1u);
    if (l < 5) {   // cols l*8 .. l*8+8 of 40
        size_t base = (size_t)node * 40 + l * 8;
        float4 o1, o2;
        o1.x = f0 * r + Q[base + 0]; o1.y = f1 * r + Q[base + 1];
        o1.z = f2 * r + Q[base + 2]; o1.w = f3 * r + Q[base + 3];
        o2.x = f4 * r + Q[base + 4]; o2.y = f5 * r + Q[base + 5];
        o2.z = f6 * r + Q[base + 6]; o2.w = f7 * r + Q[base + 7];
        *(float4*)(out + base) = o1;
        *(float4*)(out + base + 4) = o2;
    }
}

// ---------------- BN finalize (reduce 32 banks) ------------------------------
__global__ void bn_finalize(const float* __restrict__ sums, const float* __restrict__ g,
                            const float* __restrict__ be, float* __restrict__ sc,
                            float* __restrict__ sh) {
    __shared__ float lds[256];
    int t = threadIdx.x;
    float s = 0.f;
#pragma unroll 8
    for (int bk = 0; bk < NBANK; bk++) s += sums[bk * 256 + t];
    lds[t] = s;
    __syncthreads();
    if (t < 128) {
        float inv_n = 1.0f / (float)N_NODES;
        float mu = lds[t] * inv_n;
        float var = lds[128 + t] * inv_n - mu * mu;
        float sf = g[t] * rsqrtf(var + EPS);
        sc[t] = sf;
        sh[t] = be[t] - mu * sf;
    }
}

// ---------------- host ----------------
extern "C" void kernel_launch(void* const* d_in, const int* in_sizes, int n_in,
                              void* d_out, int out_size, void* d_ws, size_t ws_size,
                              hipStream_t stream) {
    const float* x   = (const float*)d_in[0];
    const int* ei    = (const int*)d_in[1];     // [2, E] int32: row 0 = src, row 1 = dst
    const float* Wl0 = (const float*)d_in[2];
    const float* Wr0 = (const float*)d_in[3];
    const float* Wl1 = (const float*)d_in[4];
    const float* Wr1 = (const float*)d_in[5];
    const float* Wl2 = (const float*)d_in[6];
    const float* Wr2 = (const float*)d_in[7];
    const float* b2  = (const float*)d_in[8];
    const float* g0  = (const float*)d_in[9];
    const float* be0 = (const float*)d_in[10];
    const float* g1  = (const float*)d_in[11];
    const float* be1 = (const float*)d_in[12];

    char* ws = (char*)d_ws;
    size_t off = 0;
    auto alloc = [&](size_t bytes) -> void* {
        void* p = ws + off;
        off += (bytes + 4095) & ~(size_t)4095;
        return p;
    };

    const size_t NB16 = (size_t)N_NODES * 128 * 2;  // 25.6 MB bf16 feature buffer
    unsigned short* xb   = (unsigned short*)alloc(NB16);   // x bf16; reused as Q (fp32 16MB)
    unsigned short* C0b  = (unsigned short*)alloc(NB16);   // layer-0 pre-BN C; reused as P40
    unsigned short* C1b  = (unsigned short*)alloc(NB16);   // layer-1 pre-BN C
    float* sums0         = (float*)alloc(NBANK * 256 * 4); // contiguous with sums1
    float* sums1         = (float*)alloc(NBANK * 256 * 4);
    unsigned int* rowptr = (unsigned int*)alloc((size_t)(N_NODES + 1) * 4);
    int* srclist         = (int*)alloc((size_t)N_EDGES * 4);
    unsigned int* ebuf   = (unsigned int*)alloc((size_t)N_EDGES * 4);
    unsigned int* bhist  = (unsigned int*)alloc((size_t)NBUCK * HB_BLOCKS * 4);
    float* sc            = (float*)alloc(128 * 4);
    float* sh            = (float*)alloc(128 * 4);
    unsigned short* W0p  = (unsigned short*)alloc(8 * 8 * 64 * 8 * 2);
    unsigned short* W1p  = (unsigned short*)alloc(8 * 8 * 64 * 8 * 2);
    unsigned short* W2p  = (unsigned short*)alloc(3 * 8 * 64 * 8 * 2);

    unsigned short* P40  = C0b;           // 8 MB, C0 dead after layer-1 gemm
    float* Q             = (float*)xb;    // 16 MB, xb dead after layer-0 gemm

    const int* srcp = ei;
    const int* dstp = ei + N_EDGES;

    hipMemsetAsync(sums0, 0, (size_t)2 * NBANK * 256 * 4, stream);

    // fused cvt + coarse hist + weight pack
    prep_k<<<13060, 256, 0, stream>>>(x, xb, dstp, bhist,
                                      Wl0, Wr0, Wl1, Wr1, Wl2, Wr2, W0p, W1p, W2p);

    // CSR: coarse partition (250 buckets) then per-bucket LDS counting sort
    bscan<<<1, 1024, 0, stream>>>(bhist);
    bscatter<<<HB_BLOCKS, 256, 0, stream>>>(srcp, dstp, bhist, ebuf);
    bucket_sort_k<<<NBUCK, 256, 0, stream>>>(ebuf, bhist, rowptr, srclist);

    // layer 0: agg+gemm from x (no input BN) -> C0, stats0
    gemm2f_k<0><<<6250, 256, 0, stream>>>(xb, rowptr, srclist, nullptr, nullptr, W0p, C0b, sums0);
    bn_finalize<<<1, 256, 0, stream>>>(sums0, g0, be0, sc, sh);

    // layer 1: agg+gemm from C0 with inline relu(bn0) -> C1, stats1
    gemm2f_k<1><<<6250, 256, 0, stream>>>(C0b, rowptr, srclist, sc, sh, W1p, C1b, sums1);
    bn_finalize<<<1, 256, 0, stream>>>(sums1, g1, be1, sc, sh);

    // layer 2: transform-first (mean is linear)
    dense_k<<<6250, 192, 0, stream>>>(C1b, sc, sh, W2p, b2, P40, Q);
    agg40_k<<<3125, 256, 0, stream>>>(P40, rowptr, srclist, Q, (float*)d_out);

    (void)in_sizes; (void)n_in; (void)out_size; (void)ws_size;
}